// Round 6
// baseline (428.747 us; speedup 1.0000x reference)
//
#include <hip/hip_runtime.h>
#include <hip/hip_bf16.h>
#include <math.h>
#include <stdint.h>

#define BB 2
#define SS 2048
#define DD 512
#define HH 8
#define NTOK (BB*SS)      // 4096 tokens
#define NQKV (3*HH*DD)    // 12288
#define BHD  (HH*DD)      // 4096
#define NBH  (BB*HH)      // 16
#define NTILE 136         // tri(16): causal 128x128 tiles per (b,h)

typedef __attribute__((ext_vector_type(8))) short short8v;
typedef __attribute__((ext_vector_type(4))) float floatx4;

__device__ __forceinline__ unsigned short f2bf(float f) {
  unsigned int u = __builtin_bit_cast(unsigned int, f);
  u = (u + 0x7FFFu + ((u >> 16) & 1u)) >> 16;   // RNE
  return (unsigned short)u;
}
__device__ __forceinline__ float bf2f(unsigned short s) {
  unsigned int u = ((unsigned int)s) << 16;
  return __builtin_bit_cast(float, u);
}
__device__ __forceinline__ void async16(const void* g, void* l) {
  __builtin_amdgcn_global_load_lds(
      (const __attribute__((address_space(1))) unsigned int*)g,
      (__attribute__((address_space(3))) unsigned int*)l, 16, 0, 0);
}
#define WAITVM(N) asm volatile("s_waitcnt vmcnt(" #N ")" ::: "memory")
#define BAR() __builtin_amdgcn_s_barrier()

// ---------------- prep: q -> bf16 ----------------
__global__ void k_convert_q(const float* __restrict__ q, unsigned short* __restrict__ qbf) {
  int i = (blockIdx.x * 256 + threadIdx.x) * 4;
  const float4 v = *(const float4*)&q[i];
  ushort4 o;
  o.x = f2bf(v.x); o.y = f2bf(v.y); o.z = f2bf(v.z); o.w = f2bf(v.w);
  *(ushort4*)&qbf[i] = o;
}

// ---------------- prep: RoPE table ropeT[s][dp] = {cos, sin} (f32, s-major for coalesced epilogue) ----------------
__global__ void k_rope_tab(float* __restrict__ rope) {
  const int idx = blockIdx.x * 256 + threadIdx.x;   // s*256 + dp
  const int s = idx >> 8, dp = idx & 255;
  const float inv = exp2f(-13.287712379549449f * (1.0f/256.0f) * (float)dp);
  float sn, cs;
  __sincosf((float)s * inv, &sn, &cs);
  rope[(size_t)idx * 2]     = cs;
  rope[(size_t)idx * 2 + 1] = sn;
}

// ---------------- prep: transpose weights to B^T bf16 (Wq pre-scaled by 1/sqrt(512)) ----------------
__global__ void k_prep_w(const float* __restrict__ Wq, const float* __restrict__ Wk,
                         const float* __restrict__ Wv, const float* __restrict__ Wo,
                         unsigned short* __restrict__ Wcat, unsigned short* __restrict__ Wot) {
  __shared__ float t[32][33];
  const int z = blockIdx.z;
  const float* in; unsigned short* out; int inLD, outLD;
  float sc = 1.0f;
  if (z < 24) {
    int tsel = z / 8, h = z % 8;
    const float* w = (tsel == 0) ? Wq : (tsel == 1) ? Wk : Wv;
    if (tsel == 0) sc = 0.044194173824159216f;   // 1/sqrt(512) folded into Wq
    in = w + (size_t)h * DD * DD;
    out = Wcat + ((size_t)tsel * BHD + (size_t)h * DD) * DD;
    inLD = DD; outLD = DD;
  } else {
    int k = z - 24;
    in = Wo + (size_t)k * DD * DD;
    out = Wot + (size_t)k * DD;
    inLD = DD; outLD = BHD;
  }
  const int tx = threadIdx.x, ty = threadIdx.y;
  const int bx = blockIdx.x * 32, by = blockIdx.y * 32;
  for (int kk = 0; kk < 4; ++kk)
    t[ty + 8*kk][tx] = in[(size_t)(by + ty + 8*kk) * inLD + bx + tx];
  __syncthreads();
  for (int kk = 0; kk < 4; ++kk)
    out[(size_t)(bx + ty + 8*kk) * outLD + by + tx] = f2bf(t[tx][ty + 8*kk] * sc);
}

// ---------------- GEMM1: QKV projection, 128x128 tile (m103-optimal shape), 3 blocks/CU,
//                  depth-2 (3-buffer) counted-vmcnt pipeline, table-RoPE epilogue ----------------
__global__ __launch_bounds__(256, 3)
void k_qkv(const unsigned short* __restrict__ Abf, const unsigned short* __restrict__ Bt,
           const float* __restrict__ ropeT,
           unsigned short* __restrict__ Qr, unsigned short* __restrict__ Kr,
           unsigned short* __restrict__ Vt) {
  __shared__ short As[3][128*32];   // 24 KB
  __shared__ short Bs[3][128*32];   // 24 KB -> 48 KB total, 3 blocks/CU
  const int tid = threadIdx.x;
  // XCD chunk swizzle: 3072 blocks -> 8 chunks of 384 (12 n-panels x all 32 m; A 4MB L2-resident)
  const int lin = blockIdx.y * 32 + blockIdx.x;
  const int lin2 = (lin & 7) * 384 + (lin >> 3);
  const int m0 = (lin2 & 31) * 128;
  const int n0 = (lin2 >> 5) * 128;
  const int wave = tid >> 6, lane = tid & 63, qd = lane >> 4, c = lane & 15;
  const int wm = (wave >> 1) * 64, wn = (wave & 1) * 64;
  floatx4 acc[4][4] = {};
  const int e0 = tid * 8;
  const int r0 = e0 >> 5, c0 = e0 & 31;   // r0 in [0,64)
  auto STAGE = [&](int buf, int k0) {
    async16(&Abf[(size_t)(m0 + r0     ) * 512 + k0 + c0], &As[buf][e0]);
    async16(&Abf[(size_t)(m0 + r0 + 64) * 512 + k0 + c0], &As[buf][e0 + 2048]);
    async16(&Bt [(size_t)(n0 + r0     ) * 512 + k0 + c0], &Bs[buf][e0]);
    async16(&Bt [(size_t)(n0 + r0 + 64) * 512 + k0 + c0], &Bs[buf][e0 + 2048]);
  };
  STAGE(0, 0);
  STAGE(1, 32);
#pragma unroll
  for (int i = 0; i < 16; ++i) {
    const int cur = i % 3;
    if (i < 14)      { STAGE((i + 2) % 3, (i + 2) * 32); WAITVM(8); }  // 2 stages in flight
    else if (i == 14){ WAITVM(4); }
    else             { WAITVM(0); }
    BAR();
    short8v a[4], b[4];
    for (int mt = 0; mt < 4; ++mt) a[mt] = *(const short8v*)&As[cur][(wm + mt*16 + c)*32 + qd*8];
    for (int nt = 0; nt < 4; ++nt) b[nt] = *(const short8v*)&Bs[cur][(wn + nt*16 + c)*32 + qd*8];
    for (int mt = 0; mt < 4; ++mt)
      for (int nt = 0; nt < 4; ++nt)
        acc[mt][nt] = __builtin_amdgcn_mfma_f32_16x16x32_bf16(a[mt], b[nt], acc[mt][nt], 0, 0, 0);
    BAR();                                                  // reads of cur done before its overwrite
  }
  const int tsel = n0 >> 12;
  const int h = (n0 >> 9) & 7;
  const int bat = m0 >> 11;
  const int bh = bat * HH + h;
  const int dloc = (n0 & 511) + wn;
  if (tsel < 2) {
    unsigned short* dst = (tsel == 0) ? Qr : Kr;
    const int dp0 = (dloc >> 1) + (c >> 1);
    const unsigned int sgn = (c & 1) ? 0u : 0x80000000u;  // even d: res = v*cs - p*sn
    const bool evenlane = !(c & 1);
    for (int mt = 0; mt < 4; ++mt) {
      const int mrow = (m0 & 2047) + wm + mt*16 + qd*4;
      for (int r = 0; r < 4; ++r) {
        const int s = mrow + r;
        const float2* rp = (const float2*)&ropeT[((size_t)s * 256 + dp0) * 2];
        const size_t ob = ((size_t)bh * SS + s) * DD;
        for (int nt = 0; nt < 4; ++nt) {
          const float2 tt = rp[nt * 8];             // lanes read contiguous dp -> 64B/line
          const float v = acc[mt][nt][r];
          float p = __shfl_xor(v, 1, 64);
          p = __builtin_bit_cast(float, __builtin_bit_cast(unsigned int, p) ^ sgn);
          const float res = fmaf(p, tt.y, v * tt.x);
          const float pair = __shfl_xor(res, 1, 64); // odd lane's result -> even lane
          if (evenlane) {
            ushort2 u2; u2.x = f2bf(res); u2.y = f2bf(pair);
            *(ushort2*)&dst[ob + dloc + nt*16 + c] = u2;
          }
        }
      }
    }
  } else {
    for (int nt = 0; nt < 4; ++nt) {
      const int d = dloc + nt*16 + c;
      const size_t vbase = ((size_t)bh * DD + d) * SS;
      for (int mt = 0; mt < 4; ++mt) {
        const int s = (m0 & 2047) + wm + mt*16 + qd*4;
        ushort4 u;
        u.x = f2bf(acc[mt][nt][0]); u.y = f2bf(acc[mt][nt][1]);
        u.z = f2bf(acc[mt][nt][2]); u.w = f2bf(acc[mt][nt][3]);
        *(ushort4*)&Vt[vbase + s] = u;
      }
    }
  }
}

// ---------------- pass A: E = exp(S) panels (bf16, causal triangle) + row sums l_z ----------------
// Depth-2 (3-buffer) counted-vmcnt pipeline; staging 48 KB unioned with ET (34 KB).
__global__ __launch_bounds__(256)
void k_scores(const unsigned short* __restrict__ Qr, const unsigned short* __restrict__ Kr,
              unsigned short* __restrict__ Eg, float* __restrict__ lsum) {
  __shared__ short UN[24576];   // union: A[3](24KB)+B[3](24KB) = 48 KB | ET 128x136 (34 KB)
  unsigned short* ET = (unsigned short*)UN;
  const int tid = threadIdx.x;
  const int lin = blockIdx.y * 136 + blockIdx.x;        // 2176 blocks
  const int lin2 = (lin & 7) * 272 + (lin >> 3);        // 8 chunks of 272 (= 2 bh)
  const int bh = lin2 / 136;
  const int t = lin2 % 136;
  int zb = 0;
  while (((zb + 1) * (zb + 2)) / 2 <= t) ++zb;
  const int st = t - (zb * (zb + 1)) / 2;
  const int z0 = zb * 128, s0 = st * 128;
  const int wave = tid >> 6, lane = tid & 63, qd = lane >> 4, c = lane & 15;
  const int wm = (wave >> 1) * 64, wn = (wave & 1) * 64;
  const size_t qb = (size_t)bh * SS * DD;
  floatx4 acc[4][4] = {};
  const int e0 = tid * 8, e1 = e0 + 2048;
  const int r0 = e0 >> 5, c0 = e0 & 31, r1 = e1 >> 5, c1 = e1 & 31;
  auto STAGE = [&](int buf, int k0) {
    short* A = UN + buf * 4096;
    short* B = UN + 12288 + buf * 4096;
    async16(&Qr[qb + (size_t)(z0 + r0) * 512 + k0 + c0], &A[e0]);
    async16(&Qr[qb + (size_t)(z0 + r1) * 512 + k0 + c1], &A[e1]);
    async16(&Kr[qb + (size_t)(s0 + r0) * 512 + k0 + c0], &B[e0]);
    async16(&Kr[qb + (size_t)(s0 + r1) * 512 + k0 + c1], &B[e1]);
  };
  STAGE(0, 0);
  STAGE(1, 32);
#pragma unroll
  for (int kk = 0; kk < 16; ++kk) {
    const int cur = kk % 3;
    if (kk < 14)      { STAGE((kk + 2) % 3, (kk + 2) * 32); WAITVM(8); }
    else if (kk == 14){ WAITVM(4); }
    else              { WAITVM(0); }
    BAR();
    const short* Asp = UN + cur * 4096;
    const short* Bsp = UN + 12288 + cur * 4096;
    short8v a[4], bfr[4];
    for (int mt = 0; mt < 4; ++mt) a[mt]   = *(const short8v*)&Asp[(wm + mt*16 + c)*32 + qd*8];
    for (int nt = 0; nt < 4; ++nt) bfr[nt] = *(const short8v*)&Bsp[(wn + nt*16 + c)*32 + qd*8];
    for (int mt = 0; mt < 4; ++mt)
      for (int nt = 0; nt < 4; ++nt)
        acc[mt][nt] = __builtin_amdgcn_mfma_f32_16x16x32_bf16(a[mt], bfr[nt], acc[mt][nt], 0, 0, 0);
    BAR();
  }
  const bool diag = (st == zb);
  for (int mt = 0; mt < 4; ++mt) {
    const int zl = wm + mt*16 + qd*4;
    float rs[4] = {0.f, 0.f, 0.f, 0.f};
    for (int nt = 0; nt < 4; ++nt) {
      const int sl = wn + nt*16 + c;
      for (int r = 0; r < 4; ++r) {
        float ev = __expf(acc[mt][nt][r]);
        if (diag && (sl > zl + r)) ev = 0.f;
        acc[mt][nt][r] = ev;
        rs[r] += ev;
      }
    }
    for (int off = 1; off < 16; off <<= 1)
      for (int r = 0; r < 4; ++r) rs[r] += __shfl_xor(rs[r], off, 64);
    if (c == 0)
      for (int r = 0; r < 4; ++r)
        atomicAdd(&lsum[(size_t)bh * SS + z0 + zl + r], rs[r]);
  }
  // final loop barrier passed by all waves -> safe to overwrite UN with ET
  for (int mt = 0; mt < 4; ++mt) {
    const int zl = wm + mt*16 + qd*4;
    for (int nt = 0; nt < 4; ++nt) {
      const int sl = wn + nt*16 + c;
      ushort4 u;
      u.x = f2bf(acc[mt][nt][0]); u.y = f2bf(acc[mt][nt][1]);
      u.z = f2bf(acc[mt][nt][2]); u.w = f2bf(acc[mt][nt][3]);
      *(ushort4*)&ET[sl * 136 + zl] = u;
    }
  }
  __syncthreads();
  const size_t tb = ((size_t)bh * NTILE + t) * 16384;
  for (int it = 0; it < 8; ++it) {
    const int e = it * 2048 + tid * 8;
    const int row = e >> 7, col = e & 127;
    *(short8v*)&Eg[tb + row * 128 + col] = *(const short8v*)&ET[row * 136 + col];
  }
}

// ---------------- scale V by 1/l_z in place: Vs[d][z] = V^T[d][z] / l[z] ----------------
__global__ void k_vscale(unsigned short* __restrict__ Vt, const float* __restrict__ lsum) {
  const int idx = (blockIdx.x * 256 + threadIdx.x) * 8;
  const int z = idx & (SS - 1);
  const int bh = idx >> 20;
  short8v v = *(const short8v*)&Vt[idx];
  const float* lp = &lsum[(size_t)bh * SS + z];
  short8v o;
  for (int i = 0; i < 8; ++i)
    o[i] = (short)f2bf(bf2f((unsigned short)v[i]) / lp[i]);
  *(short8v*)&Vt[idx] = o;
}

// ---------------- pass B: out^T(128d x 128s) = sum_z Vs^T(d,z) E^T(s,z) — pure GEMM ----------------
// Pair-balanced; depth-2 (3-buffer) pipeline with 32-z steps (48 KB LDS).
__global__ __launch_bounds__(256)
void k_pv(const unsigned short* __restrict__ Eg, const unsigned short* __restrict__ Vs,
          unsigned short* __restrict__ Ocat) {
  __shared__ short Vl[3][128*32];   // 24 KB
  __shared__ short El[3][128*32];   // 24 KB
  const int tid = threadIdx.x;
  const int lin = (blockIdx.z * 8 + blockIdx.y) * 4 + blockIdx.x;   // 512 blocks
  const int lin2 = (lin & 7) * 64 + (lin >> 3);                     // 8 chunks of 64 (= 2 bh)
  const int d0 = (lin2 & 3) * 128;
  const int pr = (lin2 >> 2) & 7;     // pair index 0..7
  const int bh = lin2 >> 5;
  const int bat = bh >> 3, h = bh & 7;
  const int wave = tid >> 6, lane = tid & 63, qd = lane >> 4, c = lane & 15;
  const int wm = (wave >> 1) * 64, wn = (wave & 1) * 64;
  const size_t vbb = (size_t)bh * DD * SS;
  const int e = tid * 8;
  auto STAGE = [&](int buf, int zq, int st) {              // zq = z-quarter index (32 z each)
    const int zb = st + (zq >> 2);
    const size_t tb = ((size_t)bh * NTILE + (zb * (zb + 1)) / 2 + st) * 16384;
    const int zin = (zq & 3) * 32;
    const int zbase = zb * 128 + zin;
    for (int i = 0; i < 2; ++i) {
      const int ee = e + i * 2048;
      const int row = ee >> 5, col = ee & 31;
      async16(&Vs[vbb + (size_t)(d0 + row) * SS + zbase + col], &Vl[buf][row * 32 + col]);
      async16(&Eg[tb + (size_t)row * 128 + zin + col], &El[buf][row * 32 + col]);
    }
  };
  for (int sel = 0; sel < 2; ++sel) {
    const int st = sel ? (15 - pr) : pr;
    const int s0 = st * 128;
    floatx4 acc[4][4] = {};
    const int nst = (16 - st) * 4;     // 32-z steps (>= 4)
    STAGE(0, 0, st);
    STAGE(1, 1, st);
    int cur = 0;
    for (int q2 = 0; q2 < nst; ++q2) {
      if (q2 + 2 < nst)       { STAGE(cur ? cur - 1 : 2, q2 + 2, st); WAITVM(8); }
      else if (q2 + 2 == nst) { WAITVM(4); }
      else                    { WAITVM(0); }
      BAR();
      short8v a[4], b[4];
      for (int dt = 0; dt < 4; ++dt) a[dt] = *(const short8v*)&Vl[cur][(wm + dt*16 + c)*32 + qd*8];
      for (int nt = 0; nt < 4; ++nt) b[nt] = *(const short8v*)&El[cur][(wn + nt*16 + c)*32 + qd*8];
      for (int dt = 0; dt < 4; ++dt)
        for (int nt = 0; nt < 4; ++nt)
          acc[dt][nt] = __builtin_amdgcn_mfma_f32_16x16x32_bf16(a[dt], b[nt], acc[dt][nt], 0, 0, 0);
      BAR();
      cur = (cur == 2) ? 0 : cur + 1;
    }
    for (int nt = 0; nt < 4; ++nt) {
      const int sg = s0 + wn + nt*16 + c;
      const size_t ob = ((size_t)(bat * SS + sg)) * BHD + (size_t)h * DD + d0;
      for (int dt = 0; dt < 4; ++dt) {
        const int dloc = wm + dt*16 + qd*4;
        ushort4 u;
        u.x = f2bf(acc[dt][nt][0]); u.y = f2bf(acc[dt][nt][1]);
        u.z = f2bf(acc[dt][nt][2]); u.w = f2bf(acc[dt][nt][3]);
        *(ushort4*)&Ocat[ob + dloc] = u;
      }
    }
  }
}

// ---------------- GEMM4: out += Ocat @ Wo, 128x128 tile, split-K=4, BK=32 depth-2 pipeline ----------------
__global__ __launch_bounds__(256)
void k_oproj(const unsigned short* __restrict__ Ocat, const unsigned short* __restrict__ Wot,
             float* __restrict__ out) {
  __shared__ short As[3][128*32];   // 24 KB
  __shared__ short Bs[3][128*32];   // 24 KB
  const int tid = threadIdx.x;
  const int lin = (blockIdx.z * 4 + blockIdx.y) * 32 + blockIdx.x;  // 512 blocks
  const int lin2 = (lin & 7) * 64 + (lin >> 3);
  const int m0 = (lin2 & 31) * 128;
  const int rest = lin2 >> 5;
  const int n0 = (rest & 3) * 128;
  const int ks = (rest >> 2) * 1024;
  const int wave = tid >> 6, lane = tid & 63, qd = lane >> 4, c = lane & 15;
  const int wm = (wave >> 1) * 64, wn = (wave & 1) * 64;
  floatx4 acc[4][4] = {};
  const int e0 = tid * 8, e1 = e0 + 2048;
  const int r0 = e0 >> 5, c0 = e0 & 31, r1 = e1 >> 5, c1 = e1 & 31;
  auto STAGE = [&](int buf, int k0) {
    async16(&Ocat[(size_t)(m0 + r0) * BHD + k0 + c0], &As[buf][e0]);
    async16(&Ocat[(size_t)(m0 + r1) * BHD + k0 + c1], &As[buf][e1]);
    async16(&Wot [(size_t)(n0 + r0) * BHD + k0 + c0], &Bs[buf][e0]);
    async16(&Wot [(size_t)(n0 + r1) * BHD + k0 + c1], &Bs[buf][e1]);
  };
  STAGE(0, ks);
  STAGE(1, ks + 32);
  int cur = 0;
  for (int i = 0; i < 32; ++i) {
    if (i < 30)      { STAGE(cur ? cur - 1 : 2, ks + (i + 2) * 32); WAITVM(8); }
    else if (i == 30){ WAITVM(4); }
    else             { WAITVM(0); }
    BAR();
    short8v a[4], b[4];
    for (int mt = 0; mt < 4; ++mt) a[mt] = *(const short8v*)&As[cur][(wm + mt*16 + c)*32 + qd*8];
    for (int nt = 0; nt < 4; ++nt) b[nt] = *(const short8v*)&Bs[cur][(wn + nt*16 + c)*32 + qd*8];
    for (int mt = 0; mt < 4; ++mt)
      for (int nt = 0; nt < 4; ++nt)
        acc[mt][nt] = __builtin_amdgcn_mfma_f32_16x16x32_bf16(a[mt], b[nt], acc[mt][nt], 0, 0, 0);
    BAR();
    cur = (cur == 2) ? 0 : cur + 1;
  }
  for (int mt = 0; mt < 4; ++mt) {
    const int m = m0 + wm + mt*16 + qd*4;
    for (int nt = 0; nt < 4; ++nt) {
      const int n = n0 + wn + nt*16 + c;
      for (int r = 0; r < 4; ++r)
        atomicAdd(&out[(size_t)(m + r) * DD + n], acc[mt][nt][r]);
    }
  }
}

extern "C" void kernel_launch(void* const* d_in, const int* in_sizes, int n_in,
                              void* d_out, int out_size, void* d_ws, size_t ws_size,
                              hipStream_t stream) {
  const float* q  = (const float*)d_in[0];
  const float* Wq = (const float*)d_in[1];
  const float* Wk = (const float*)d_in[2];
  const float* Wv = (const float*)d_in[3];
  const float* Wo = (const float*)d_in[4];

  // workspace layout with lifetime-based aliasing (peak ~176 MB)
  char* base = (char*)d_ws;
  unsigned short* Eg   = (unsigned short*)base;                       // 71,303,168 B
  unsigned short* qbf  = (unsigned short*)base;                       // overlay (dies after k_qkv)
  unsigned short* Wcat = (unsigned short*)(base + 4194304);           // overlay (dies after k_qkv)
  float*          rope = (float*)(base + 16777216);                   // 4 MB overlay (dies after k_qkv)
  char* p = base + 71303168;
  unsigned short* Wot  = (unsigned short*)p; p += 4194304;
  unsigned short* Qr   = (unsigned short*)p;
  unsigned short* Ocat = (unsigned short*)p; p += 33554432;           // overlays Qr (dead after k_scores)
  unsigned short* Kr   = (unsigned short*)p; p += 33554432;
  unsigned short* Vt   = (unsigned short*)p; p += 33554432;
  float*          lsum = (float*)p;

  hipMemsetAsync(lsum, 0, (size_t)NBH * SS * 4, stream);
  hipMemsetAsync(d_out, 0, (size_t)NTOK * DD * 4, stream);

  k_convert_q<<<NTOK*DD/1024, 256, 0, stream>>>(q, qbf);
  k_rope_tab<<<SS*256/256, 256, 0, stream>>>(rope);
  k_prep_w<<<dim3(16,16,32), dim3(32,8), 0, stream>>>(Wq, Wk, Wv, Wo, Wcat, Wot);
  k_qkv<<<dim3(32,96), 256, 0, stream>>>(qbf, Wcat, rope, Qr, Kr, Vt);
  k_scores<<<dim3(NTILE,16), 256, 0, stream>>>(Qr, Kr, Eg, lsum);
  k_vscale<<<NBH*DD*SS/(256*8), 256, 0, stream>>>(Vt, lsum);
  k_pv<<<dim3(4,8,16), 256, 0, stream>>>(Eg, Vt, Ocat);
  k_oproj<<<dim3(32,4,4), 256, 0, stream>>>(Ocat, Wot, (float*)d_out);
}

// Round 8
// 360.812 us; speedup vs baseline: 1.1883x; 1.1883x over previous
//
#include <hip/hip_runtime.h>
#include <hip/hip_bf16.h>
#include <math.h>
#include <stdint.h>

#define BB 2
#define SS 2048
#define DD 512
#define HH 8
#define NTOK (BB*SS)      // 4096 tokens
#define NQKV (3*HH*DD)    // 12288
#define BHD  (HH*DD)      // 4096
#define NBH  (BB*HH)      // 16
#define NTILE 136         // tri(16): causal 128x128 tiles per (b,h)

typedef __attribute__((ext_vector_type(8))) short short8v;
typedef __attribute__((ext_vector_type(4))) float floatx4;

__device__ __forceinline__ unsigned short f2bf(float f) {
  unsigned int u = __builtin_bit_cast(unsigned int, f);
  u = (u + 0x7FFFu + ((u >> 16) & 1u)) >> 16;   // RNE
  return (unsigned short)u;
}
__device__ __forceinline__ float bf2f(unsigned short s) {
  unsigned int u = ((unsigned int)s) << 16;
  return __builtin_bit_cast(float, u);
}
__device__ __forceinline__ void async16(const void* g, void* l) {
  __builtin_amdgcn_global_load_lds(
      (const __attribute__((address_space(1))) unsigned int*)g,
      (__attribute__((address_space(3))) unsigned int*)l, 16, 0, 0);
}
#define WAITVM(N) asm volatile("s_waitcnt vmcnt(" #N ")" ::: "memory")
#define BAR() __builtin_amdgcn_s_barrier()

// ---------------- prep: q -> bf16 ----------------
__global__ void k_convert_q(const float* __restrict__ q, unsigned short* __restrict__ qbf) {
  int i = (blockIdx.x * 256 + threadIdx.x) * 4;
  const float4 v = *(const float4*)&q[i];
  ushort4 o;
  o.x = f2bf(v.x); o.y = f2bf(v.y); o.z = f2bf(v.z); o.w = f2bf(v.w);
  *(ushort4*)&qbf[i] = o;
}

// ---------------- prep: RoPE table ropeT[s][dp] = {cos, sin} ----------------
__global__ void k_rope_tab(float* __restrict__ rope) {
  const int idx = blockIdx.x * 256 + threadIdx.x;   // s*256 + dp
  const int s = idx >> 8, dp = idx & 255;
  const float inv = exp2f(-13.287712379549449f * (1.0f/256.0f) * (float)dp);
  float sn, cs;
  __sincosf((float)s * inv, &sn, &cs);
  rope[(size_t)idx * 2]     = cs;
  rope[(size_t)idx * 2 + 1] = sn;
}

// ---------------- prep: transpose weights to B^T bf16 (Wq pre-scaled by 1/sqrt(512)) ----------------
__global__ void k_prep_w(const float* __restrict__ Wq, const float* __restrict__ Wk,
                         const float* __restrict__ Wv, const float* __restrict__ Wo,
                         unsigned short* __restrict__ Wcat, unsigned short* __restrict__ Wot) {
  __shared__ float t[32][33];
  const int z = blockIdx.z;
  const float* in; unsigned short* out; int inLD, outLD;
  float sc = 1.0f;
  if (z < 24) {
    int tsel = z / 8, h = z % 8;
    const float* w = (tsel == 0) ? Wq : (tsel == 1) ? Wk : Wv;
    if (tsel == 0) sc = 0.044194173824159216f;   // 1/sqrt(512) folded into Wq
    in = w + (size_t)h * DD * DD;
    out = Wcat + ((size_t)tsel * BHD + (size_t)h * DD) * DD;
    inLD = DD; outLD = DD;
  } else {
    int k = z - 24;
    in = Wo + (size_t)k * DD * DD;
    out = Wot + (size_t)k * DD;
    inLD = DD; outLD = BHD;
  }
  const int tx = threadIdx.x, ty = threadIdx.y;
  const int bx = blockIdx.x * 32, by = blockIdx.y * 32;
  for (int kk = 0; kk < 4; ++kk)
    t[ty + 8*kk][tx] = in[(size_t)(by + ty + 8*kk) * inLD + bx + tx];
  __syncthreads();
  for (int kk = 0; kk < 4; ++kk)
    out[(size_t)(bx + ty + 8*kk) * outLD + by + tx] = f2bf(t[tx][ty + 8*kk] * sc);
}

// ---------------- GEMM1: QKV projection — 256x256 tile, 8 waves, BK=64, 8-phase schedule ----------------
// T3+T4 (counted vmcnt, 1 half-tile stage/phase) + T2 (XOR row-swizzle, both-sides) + T5 (setprio).
// Safety ledger (per iteration it, tiles kt0=2it in dbuf0, kt1=2it+1 in dbuf1):
//   reads dbuf0 end at P2 (lgkmcnt before P2 trailing BAR); stages into dbuf0 at P3..P6 -> no overwrite race.
//   reads dbuf1 end at P6; stages into dbuf1 at P7 and next-iter P0..P2 -> safe.
//   WAITVM(2) at end of P3 leaves only P3's stage in flight -> tile kt1 (staged P7',P0,P1,P2) landed before P4 reads.
//   WAITVM(2) at end of P7 -> tile kt0+2 (staged P3..P6) landed before next-iter P0 reads.
//   Last iter: no stages for tiles>=8; P3 wait becomes WAITVM(0) so tile 7's last halves are drained.
__global__ __launch_bounds__(512, 1)
void k_qkv(const unsigned short* __restrict__ Abf, const unsigned short* __restrict__ Bt,
           const float* __restrict__ ropeT,
           unsigned short* __restrict__ Qr, unsigned short* __restrict__ Kr,
           unsigned short* __restrict__ Vt) {
  __shared__ short A_lds[2][2][128*64];   // [dbuf][half] 16 KB each -> 64 KB
  __shared__ short B_lds[2][2][128*64];   // 64 KB  (total 128 KB)
  const int tid = threadIdx.x;
  // XCD chunk swizzle: 768 blocks -> 8 chunks of 96 (6 n-panels x 16 m; A 4MB L2-resident per chunk)
  const int lin2 = (blockIdx.x & 7) * 96 + (blockIdx.x >> 3);
  const int m0 = (lin2 & 15) * 256;
  const int n0 = (lin2 >> 4) * 256;
  const int wave = tid >> 6, lane = tid & 63, qd = lane >> 4, c = lane & 15;
  const int wm = (wave >> 2) * 128;        // 2 M wave-rows
  const int wn = (wave & 3) * 64;          // 4 N wave-cols
  const int Ha = wm >> 7;                  // A half this wave reads
  const int Hb = wn >> 7;                  // B half this wave reads
  const int brw = (wn & 64) + c;           // B row base within half (+NH*32+nf*16)
  const int cw = c & 7;
  const int s0q = (qd ^ cw) * 8;           // swizzled k-slot (kh=0), shorts
  const int s1q = ((4 | qd) ^ cw) * 8;     // kh=1
  // staging: thread t covers rows trow, trow+64 of a 128x64 half-tile; source col pre-swizzled
  const int trow = tid >> 3;               // 0..63
  const int scol = ((tid & 7) ^ (trow & 7)) * 8;
  const int tlin = tid * 8;                // dest shorts offset (linear)
  floatx4 acc[8][4] = {};
  short8v ar[4][2], br0[2][2], br1[2][2];

#define STG_A(T, H) if ((T) < 8) { \
    async16(&Abf[(size_t)(m0 + (H)*128 + trow     ) * 512 + (T)*64 + scol], &A_lds[(T)&1][H][tlin]); \
    async16(&Abf[(size_t)(m0 + (H)*128 + trow + 64) * 512 + (T)*64 + scol], &A_lds[(T)&1][H][tlin + 4096]); }
#define STG_B(T, H) if ((T) < 8) { \
    async16(&Bt [(size_t)(n0 + (H)*128 + trow     ) * 512 + (T)*64 + scol], &B_lds[(T)&1][H][tlin]); \
    async16(&Bt [(size_t)(n0 + (H)*128 + trow + 64) * 512 + (T)*64 + scol], &B_lds[(T)&1][H][tlin + 4096]); }

#define PH(DB, MH, NH, BR, DOA, DOB, STAGE, WAITC) { \
    if (DOA) { \
      _Pragma("unroll") for (int mf = 0; mf < 4; ++mf) { \
        const int ra = ((MH)*64 + mf*16 + c) * 64; \
        ar[mf][0] = *(const short8v*)&A_lds[DB][Ha][ra + s0q]; \
        ar[mf][1] = *(const short8v*)&A_lds[DB][Ha][ra + s1q]; } } \
    if (DOB) { \
      _Pragma("unroll") for (int nf = 0; nf < 2; ++nf) { \
        const int rb = (brw + (NH)*32 + nf*16) * 64; \
        BR[nf][0] = *(const short8v*)&B_lds[DB][Hb][rb + s0q]; \
        BR[nf][1] = *(const short8v*)&B_lds[DB][Hb][rb + s1q]; } } \
    STAGE; \
    BAR(); \
    asm volatile("s_waitcnt lgkmcnt(0)" ::: "memory"); \
    __builtin_amdgcn_s_setprio(1); \
    _Pragma("unroll") for (int mf = 0; mf < 4; ++mf) \
      _Pragma("unroll") for (int nf = 0; nf < 2; ++nf) { \
        acc[(MH)*4+mf][(NH)*2+nf] = __builtin_amdgcn_mfma_f32_16x16x32_bf16(ar[mf][0], BR[nf][0], acc[(MH)*4+mf][(NH)*2+nf], 0, 0, 0); \
        acc[(MH)*4+mf][(NH)*2+nf] = __builtin_amdgcn_mfma_f32_16x16x32_bf16(ar[mf][1], BR[nf][1], acc[(MH)*4+mf][(NH)*2+nf], 0, 0, 0); } \
    __builtin_amdgcn_s_setprio(0); \
    WAITC; \
    BAR(); }

  // prologue: tile0 all 4 halves + tile1 A-half0; wait so tile0 is landed (newest 2 may fly)
  STG_A(0, 0); STG_A(0, 1); STG_B(0, 0); STG_B(0, 1); STG_A(1, 0);
  WAITVM(2); BAR();

  for (int it = 0; it < 4; ++it) {
    const int t1 = 2*it + 1, t2 = 2*it + 2, t3 = 2*it + 3;
    PH(0, 0, 0, br0, 1, 1, STG_A(t1, 1), ;)
    PH(0, 0, 1, br1, 0, 1, STG_B(t1, 0), ;)
    PH(0, 1, 0, br0, 1, 0, STG_B(t1, 1), ;)
    PH(0, 1, 1, br1, 0, 0, STG_A(t2, 0), if (it < 3) { WAITVM(2); } else { WAITVM(0); })
    PH(1, 0, 0, br0, 1, 1, STG_A(t2, 1), ;)
    PH(1, 0, 1, br1, 0, 1, STG_B(t2, 0), ;)
    PH(1, 1, 0, br0, 1, 0, STG_B(t2, 1), ;)
    PH(1, 1, 1, br1, 0, 0, STG_A(t3, 0), if (it < 3) { WAITVM(2); })
  }
#undef PH
#undef STG_A
#undef STG_B

  const int tsel = n0 >> 12;
  const int h = (n0 >> 9) & 7;
  const int bat = m0 >> 11;
  const int bh = bat * HH + h;
  const int colw = (n0 & 511) + wn;        // wave col base; +dof+c gives d
  if (tsel < 2) {
    unsigned short* dst = (tsel == 0) ? Qr : Kr;
    const int dp0 = (colw >> 1) + (c >> 1);
    const unsigned int sgn = (c & 1) ? 0u : 0x80000000u;  // even d: res = v*cs - p*sn
    for (int mi = 0; mi < 8; ++mi) {
      const int mrow = (m0 & 2047) + wm + (mi >> 2)*64 + (mi & 3)*16 + qd*4;
      for (int r = 0; r < 4; ++r) {
        const int s = mrow + r;
        const float2* rp = (const float2*)&ropeT[((size_t)s * 256 + dp0) * 2];
        const size_t ob = ((size_t)bh * SS + s) * DD;
        for (int ni = 0; ni < 4; ++ni) {
          const int dof = (ni >> 1)*32 + (ni & 1)*16;
          const float2 tt = rp[dof >> 1];             // lanes read contiguous dp
          const float v = acc[mi][ni][r];
          float p = __shfl_xor(v, 1, 64);
          p = __builtin_bit_cast(float, __builtin_bit_cast(unsigned int, p) ^ sgn);
          dst[ob + colw + dof + c] = f2bf(fmaf(p, tt.y, v * tt.x));
        }
      }
    }
  } else {
    for (int ni = 0; ni < 4; ++ni) {
      const int d = colw + (ni >> 1)*32 + (ni & 1)*16 + c;
      const size_t vbase = ((size_t)bh * DD + d) * SS;
      for (int mi = 0; mi < 8; ++mi) {
        const int s = (m0 & 2047) + wm + (mi >> 2)*64 + (mi & 3)*16 + qd*4;
        ushort4 u;
        u.x = f2bf(acc[mi][ni][0]); u.y = f2bf(acc[mi][ni][1]);
        u.z = f2bf(acc[mi][ni][2]); u.w = f2bf(acc[mi][ni][3]);
        *(ushort4*)&Vt[vbase + s] = u;
      }
    }
  }
}

// ---------------- pass A: E = exp(S) panels (bf16, causal triangle) + row sums l_z ----------------
// Counted-vmcnt 2-buffer pipeline; XCD chunks = 2 (b,h) per XCD so Q+K (4MB) are L2-resident.
__global__ __launch_bounds__(256)
void k_scores(const unsigned short* __restrict__ Qr, const unsigned short* __restrict__ Kr,
              unsigned short* __restrict__ Eg, float* __restrict__ lsum) {
  __shared__ short UN[17408];   // union: A[2](8KB)+B[2](8KB) = 32 KB | ET 128x136 (34 KB)
  unsigned short* ET = (unsigned short*)UN;
  const int tid = threadIdx.x;
  const int lin = blockIdx.y * 136 + blockIdx.x;        // 2176 blocks
  const int lin2 = (lin & 7) * 272 + (lin >> 3);        // 8 chunks of 272 (= 2 bh)
  const int bh = lin2 / 136;
  const int t = lin2 % 136;
  int zb = 0;
  while (((zb + 1) * (zb + 2)) / 2 <= t) ++zb;
  const int st = t - (zb * (zb + 1)) / 2;
  const int z0 = zb * 128, s0 = st * 128;
  const int wave = tid >> 6, lane = tid & 63, qd = lane >> 4, c = lane & 15;
  const int wm = (wave >> 1) * 64, wn = (wave & 1) * 64;
  const size_t qb = (size_t)bh * SS * DD;
  floatx4 acc[4][4] = {};
  const int e0 = tid * 8, e1 = e0 + 2048;
  const int r0 = e0 >> 5, c0 = e0 & 31, r1 = e1 >> 5, c1 = e1 & 31;
  auto STAGE = [&](int buf, int k0) {
    short* A = UN + buf * 4096;
    short* B = UN + 8192 + buf * 4096;
    async16(&Qr[qb + (size_t)(z0 + r0) * 512 + k0 + c0], &A[e0]);
    async16(&Qr[qb + (size_t)(z0 + r1) * 512 + k0 + c1], &A[e1]);
    async16(&Kr[qb + (size_t)(s0 + r0) * 512 + k0 + c0], &B[e0]);
    async16(&Kr[qb + (size_t)(s0 + r1) * 512 + k0 + c1], &B[e1]);
  };
  STAGE(0, 0);
  for (int kk = 0; kk < 16; ++kk) {
    const int cur = kk & 1;
    if (kk < 15) { STAGE(cur ^ 1, (kk + 1) * 32); WAITVM(4); }
    else         { WAITVM(0); }
    BAR();
    const short* Asp = UN + cur * 4096;
    const short* Bsp = UN + 8192 + cur * 4096;
    short8v a[4], bfr[4];
    for (int mt = 0; mt < 4; ++mt) a[mt]   = *(const short8v*)&Asp[(wm + mt*16 + c)*32 + qd*8];
    for (int nt = 0; nt < 4; ++nt) bfr[nt] = *(const short8v*)&Bsp[(wn + nt*16 + c)*32 + qd*8];
    for (int mt = 0; mt < 4; ++mt)
      for (int nt = 0; nt < 4; ++nt)
        acc[mt][nt] = __builtin_amdgcn_mfma_f32_16x16x32_bf16(a[mt], bfr[nt], acc[mt][nt], 0, 0, 0);
    BAR();
  }
  const bool diag = (st == zb);
  for (int mt = 0; mt < 4; ++mt) {
    const int zl = wm + mt*16 + qd*4;
    float rs[4] = {0.f, 0.f, 0.f, 0.f};
    for (int nt = 0; nt < 4; ++nt) {
      const int sl = wn + nt*16 + c;
      for (int r = 0; r < 4; ++r) {
        float ev = __expf(acc[mt][nt][r]);
        if (diag && (sl > zl + r)) ev = 0.f;
        acc[mt][nt][r] = ev;
        rs[r] += ev;
      }
    }
    for (int off = 1; off < 16; off <<= 1)
      for (int r = 0; r < 4; ++r) rs[r] += __shfl_xor(rs[r], off, 64);
    if (c == 0)
      for (int r = 0; r < 4; ++r)
        atomicAdd(&lsum[(size_t)bh * SS + z0 + zl + r], rs[r]);
  }
  // final loop barrier passed by all waves -> safe to overwrite UN with ET
  for (int mt = 0; mt < 4; ++mt) {
    const int zl = wm + mt*16 + qd*4;
    for (int nt = 0; nt < 4; ++nt) {
      const int sl = wn + nt*16 + c;
      ushort4 u;
      u.x = f2bf(acc[mt][nt][0]); u.y = f2bf(acc[mt][nt][1]);
      u.z = f2bf(acc[mt][nt][2]); u.w = f2bf(acc[mt][nt][3]);
      *(ushort4*)&ET[sl * 136 + zl] = u;
    }
  }
  __syncthreads();
  const size_t tb = ((size_t)bh * NTILE + t) * 16384;
  for (int it = 0; it < 8; ++it) {
    const int e = it * 2048 + tid * 8;
    const int row = e >> 7, col = e & 127;
    *(short8v*)&Eg[tb + row * 128 + col] = *(const short8v*)&ET[row * 136 + col];
  }
}

// ---------------- scale V by 1/l_z in place: Vs[d][z] = V^T[d][z] / l[z] ----------------
__global__ void k_vscale(unsigned short* __restrict__ Vt, const float* __restrict__ lsum) {
  const int idx = (blockIdx.x * 256 + threadIdx.x) * 8;
  const int z = idx & (SS - 1);
  const int bh = idx >> 20;
  short8v v = *(const short8v*)&Vt[idx];
  const float* lp = &lsum[(size_t)bh * SS + z];
  short8v o;
  for (int i = 0; i < 8; ++i)
    o[i] = (short)f2bf(bf2f((unsigned short)v[i]) / lp[i]);
  *(short8v*)&Vt[idx] = o;
}

// ---------------- pass B: out^T(128d x 128s) = sum_z Vs^T(d,z) E^T(s,z) — pure GEMM ----------------
// Pair-balanced; counted-vmcnt 2-buffer pipeline; XCD chunks = 2 bh per XCD (V 2MB L2-resident).
__global__ __launch_bounds__(256)
void k_pv(const unsigned short* __restrict__ Eg, const unsigned short* __restrict__ Vs,
          unsigned short* __restrict__ Ocat) {
  __shared__ short Vl[2][2][128*32];   // [buf][kc]
  __shared__ short El[2][2][128*32];
  const int tid = threadIdx.x;
  const int lin = (blockIdx.z * 8 + blockIdx.y) * 4 + blockIdx.x;   // 512 blocks
  const int lin2 = (lin & 7) * 64 + (lin >> 3);                     // 8 chunks of 64 (= 2 bh)
  const int d0 = (lin2 & 3) * 128;
  const int pr = (lin2 >> 2) & 7;     // pair index 0..7
  const int bh = lin2 >> 5;
  const int bat = bh >> 3, h = bh & 7;
  const int wave = tid >> 6, lane = tid & 63, qd = lane >> 4, c = lane & 15;
  const int wm = (wave >> 1) * 64, wn = (wave & 1) * 64;
  const size_t vbb = (size_t)bh * DD * SS;
  const int e = tid * 8;
  auto STAGE = [&](int buf, int zb, int half, int st) {
    const size_t tb = ((size_t)bh * NTILE + (zb * (zb + 1)) / 2 + st) * 16384;
    const int zbase = zb * 128 + half * 64;
    for (int i = 0; i < 4; ++i) {
      const int ee = e + i * 2048;
      const int kc = ee >> 12, row = (ee >> 5) & 127, col = ee & 31;
      async16(&Vs[vbb + (size_t)(d0 + row) * SS + zbase + kc * 32 + col], &Vl[buf][kc][row * 32 + col]);
    }
    for (int i = 0; i < 4; ++i) {
      const int ee = e + i * 2048;
      const int kc = ee >> 12, row = (ee >> 5) & 127, col = ee & 31;
      async16(&Eg[tb + (size_t)row * 128 + half * 64 + kc * 32 + col], &El[buf][kc][row * 32 + col]);
    }
  };
  for (int sel = 0; sel < 2; ++sel) {
    const int st = sel ? (15 - pr) : pr;
    const int s0 = st * 128;
    floatx4 acc[4][4] = {};
    const int nst = (16 - st) * 2;     // steps: (zb, half) flattened
    STAGE(0, st, 0, st);
    for (int q2 = 0; q2 < nst; ++q2) {
      const int cur = q2 & 1;
      if (q2 + 1 < nst) { STAGE(cur ^ 1, st + ((q2 + 1) >> 1), (q2 + 1) & 1, st); WAITVM(8); }
      else              { WAITVM(0); }
      BAR();
      for (int kc = 0; kc < 2; ++kc) {
        short8v a[4], b[4];
        for (int dt = 0; dt < 4; ++dt) a[dt] = *(const short8v*)&Vl[cur][kc][(wm + dt*16 + c)*32 + qd*8];
        for (int nt = 0; nt < 4; ++nt) b[nt] = *(const short8v*)&El[cur][kc][(wn + nt*16 + c)*32 + qd*8];
        for (int dt = 0; dt < 4; ++dt)
          for (int nt = 0; nt < 4; ++nt)
            acc[dt][nt] = __builtin_amdgcn_mfma_f32_16x16x32_bf16(a[dt], b[nt], acc[dt][nt], 0, 0, 0);
      }
      BAR();
    }
    for (int nt = 0; nt < 4; ++nt) {
      const int sg = s0 + wn + nt*16 + c;
      const size_t ob = ((size_t)(bat * SS + sg)) * BHD + (size_t)h * DD + d0;
      for (int dt = 0; dt < 4; ++dt) {
        const int dloc = wm + dt*16 + qd*4;
        ushort4 u;
        u.x = f2bf(acc[dt][nt][0]); u.y = f2bf(acc[dt][nt][1]);
        u.z = f2bf(acc[dt][nt][2]); u.w = f2bf(acc[dt][nt][3]);
        *(ushort4*)&Ocat[ob + dloc] = u;
      }
    }
  }
}

// ---------------- GEMM4: out += Ocat @ Wo, 128x128 tile, split-K=4, counted-vmcnt pipeline ----------------
__global__ __launch_bounds__(256)
void k_oproj(const unsigned short* __restrict__ Ocat, const unsigned short* __restrict__ Wot,
             float* __restrict__ out) {
  __shared__ short As[2][2][128*32];   // [buf][kc]
  __shared__ short Bs[2][2][128*32];
  const int tid = threadIdx.x;
  const int lin = (blockIdx.z * 4 + blockIdx.y) * 32 + blockIdx.x;  // 512 blocks
  const int lin2 = (lin & 7) * 64 + (lin >> 3);
  const int m0 = (lin2 & 31) * 128;
  const int rest = lin2 >> 5;
  const int n0 = (rest & 3) * 128;
  const int ks = (rest >> 2) * 1024;
  const int wave = tid >> 6, lane = tid & 63, qd = lane >> 4, c = lane & 15;
  const int wm = (wave >> 1) * 64, wn = (wave & 1) * 64;
  floatx4 acc[4][4] = {};
  const int e0 = tid * 8, e1 = e0 + 2048;
  const int r0 = e0 >> 5, c0 = e0 & 31, r1 = e1 >> 5, c1 = e1 & 31;
  auto STAGE = [&](int buf, int k0) {
    for (int kc = 0; kc < 2; ++kc) {
      const int kk = k0 + kc * 32;
      async16(&Ocat[(size_t)(m0 + r0) * BHD + kk + c0], &As[buf][kc][e0]);
      async16(&Ocat[(size_t)(m0 + r1) * BHD + kk + c1], &As[buf][kc][e1]);
      async16(&Wot [(size_t)(n0 + r0) * BHD + kk + c0], &Bs[buf][kc][e0]);
      async16(&Wot [(size_t)(n0 + r1) * BHD + kk + c1], &Bs[buf][kc][e1]);
    }
  };
  STAGE(0, ks);
  for (int t = 0; t < 16; ++t) {
    const int cur = t & 1;
    if (t < 15) { STAGE(cur ^ 1, ks + (t + 1) * 64); WAITVM(8); }
    else        { WAITVM(0); }
    BAR();
    for (int kc = 0; kc < 2; ++kc) {
      short8v a[4], b[4];
      for (int mt = 0; mt < 4; ++mt) a[mt] = *(const short8v*)&As[cur][kc][(wm + mt*16 + c)*32 + qd*8];
      for (int nt = 0; nt < 4; ++nt) b[nt] = *(const short8v*)&Bs[cur][kc][(wn + nt*16 + c)*32 + qd*8];
      for (int mt = 0; mt < 4; ++mt)
        for (int nt = 0; nt < 4; ++nt)
          acc[mt][nt] = __builtin_amdgcn_mfma_f32_16x16x32_bf16(a[mt], b[nt], acc[mt][nt], 0, 0, 0);
    }
    BAR();
  }
  for (int mt = 0; mt < 4; ++mt) {
    const int m = m0 + wm + mt*16 + qd*4;
    for (int nt = 0; nt < 4; ++nt) {
      const int n = n0 + wn + nt*16 + c;
      for (int r = 0; r < 4; ++r)
        atomicAdd(&out[(size_t)(m + r) * DD + n], acc[mt][nt][r]);
    }
  }
}

extern "C" void kernel_launch(void* const* d_in, const int* in_sizes, int n_in,
                              void* d_out, int out_size, void* d_ws, size_t ws_size,
                              hipStream_t stream) {
  const float* q  = (const float*)d_in[0];
  const float* Wq = (const float*)d_in[1];
  const float* Wk = (const float*)d_in[2];
  const float* Wv = (const float*)d_in[3];
  const float* Wo = (const float*)d_in[4];

  // workspace layout with lifetime-based aliasing (peak ~176 MB)
  char* base = (char*)d_ws;
  unsigned short* Eg   = (unsigned short*)base;                       // 71,303,168 B
  unsigned short* qbf  = (unsigned short*)base;                       // overlay (dies after k_qkv)
  unsigned short* Wcat = (unsigned short*)(base + 4194304);           // overlay (dies after k_qkv)
  float*          rope = (float*)(base + 16777216);                   // 4 MB overlay (dies after k_qkv)
  char* p = base + 71303168;
  unsigned short* Wot  = (unsigned short*)p; p += 4194304;
  unsigned short* Qr   = (unsigned short*)p;
  unsigned short* Ocat = (unsigned short*)p; p += 33554432;           // overlays Qr (dead after k_scores)
  unsigned short* Kr   = (unsigned short*)p; p += 33554432;
  unsigned short* Vt   = (unsigned short*)p; p += 33554432;
  float*          lsum = (float*)p;

  hipMemsetAsync(lsum, 0, (size_t)NBH * SS * 4, stream);
  hipMemsetAsync(d_out, 0, (size_t)NTOK * DD * 4, stream);

  k_convert_q<<<NTOK*DD/1024, 256, 0, stream>>>(q, qbf);
  k_rope_tab<<<SS*256/256, 256, 0, stream>>>(rope);
  k_prep_w<<<dim3(16,16,32), dim3(32,8), 0, stream>>>(Wq, Wk, Wv, Wo, Wcat, Wot);
  k_qkv<<<768, 512, 0, stream>>>(qbf, Wcat, rope, Qr, Kr, Vt);
  k_scores<<<dim3(NTILE,16), 256, 0, stream>>>(Qr, Kr, Eg, lsum);
  k_vscale<<<NBH*DD*SS/(256*8), 256, 0, stream>>>(Vt, lsum);
  k_pv<<<dim3(4,8,16), 256, 0, stream>>>(Eg, Vt, Ocat);
  k_oproj<<<dim3(32,4,4), 256, 0, stream>>>(Ocat, Wot, (float*)d_out);
}